// Round 1
// baseline (480.863 us; speedup 1.0000x reference)
//
#include <hip/hip_runtime.h>
#include <hip/hip_bf16.h>
#include <cstdint>
#include <cstddef>

// ---------------- types ----------------
typedef __bf16 bf16;
typedef __bf16 bf16x2 __attribute__((ext_vector_type(2)));
typedef __bf16 bf16x4 __attribute__((ext_vector_type(4)));
typedef __bf16 bf16x8 __attribute__((ext_vector_type(8)));
typedef float  floatx4 __attribute__((ext_vector_type(4)));

// problem constants
#define BB 8
#define SS 1024
#define DD 1024
#define RR 16
#define CHK 64      // chunk length
#define NCH 16      // chunks per batch (SS/CHK)

// params buffer layout (floats)
#define PP_ALPHA 0            // 16
#define PP_GAMMA 16           // 16
#define PP_GP    32           // 16*72: gamma^0..gamma^71 per r
#define PP_KKER  (32 + 16*72) // 4 (gate folded in)
#define PP_FLOATS 2048

// ---------------- small helpers ----------------
__device__ __forceinline__ float sigmoidf_(float x) { return 1.0f / (1.0f + __expf(-x)); }

__device__ __forceinline__ float gelu_f(float x) {
    float u = 0.7978845608028654f * (x + 0.044715f * x * x * x);
    float t = 1.0f - 2.0f / (__expf(2.0f * u) + 1.0f);   // tanh(u)
    return 0.5f * x * (1.0f + t);
}

__device__ __forceinline__ void g2l16(const bf16* g, bf16* l) {
    // async global->LDS, 16B per lane; LDS dest is wave-uniform base + lane*16
    __builtin_amdgcn_global_load_lds(
        (const __attribute__((address_space(1))) void*)g,
        (__attribute__((address_space(3))) void*)l, 16, 0, 0);
}

// ---------------- scalar params ----------------
__global__ void params_kernel(const float* __restrict__ decay_logit,
                              const float* __restrict__ alpha_logit,
                              const float* __restrict__ gate_logit,
                              const float* __restrict__ kbase,
                              float* __restrict__ pp) {
    int t = threadIdx.x;
    if (t < 16) {
        pp[PP_ALPHA + t] = sigmoidf_(alpha_logit[t]);       // ALPHA_CAP = 1
        float g = sigmoidf_(decay_logit[t]);
        g = fminf(fmaxf(g, 0.15f), 1.0f);
        pp[PP_GAMMA + t] = g;
        float acc = 1.0f;
        for (int p = 0; p < 72; ++p) { pp[PP_GP + t * 72 + p] = acc; acc *= g; }
    }
    if (t >= 16 && t < 20) {
        float gate = sigmoidf_(gate_logit[0]);
        pp[PP_KKER + (t - 16)] = gate * kbase[t - 16];
    }
}

// ---------------- rmsnorm1 + qk projection + l2norm ----------------
// one block handles 16 rows; U,V staged in LDS once per block
__global__ __launch_bounds__(256) void rmsqk_kernel(
    const float* __restrict__ h, const float* __restrict__ u, const float* __restrict__ v,
    const float* __restrict__ nw, const float* __restrict__ pp,
    bf16* __restrict__ hn, float* __restrict__ qa, float* __restrict__ kk) {
    __shared__ bf16 Uls[1024][32];
    __shared__ float hrow[1024];
    __shared__ float red[4];
    __shared__ float qkred[8][32];
    int t = threadIdx.x;
    for (int idx = t; idx < 16384; idx += 256) {
        int d = idx >> 4, c = idx & 15;
        Uls[d][c]      = (bf16)u[idx];
        Uls[d][16 + c] = (bf16)v[idx];
    }
    int lane = t & 63, wid = t >> 6;
    float4 wv = ((const float4*)nw)[t];
    float alpha_t = (t < 16) ? pp[PP_ALPHA + t] : 0.0f;
    size_t row0 = (size_t)blockIdx.x * 16;
    __syncthreads();
    for (int rr = 0; rr < 16; ++rr) {
        size_t row = row0 + rr;
        float4 hv = ((const float4*)(h + row * DD))[t];
        float ss = hv.x*hv.x + hv.y*hv.y + hv.z*hv.z + hv.w*hv.w;
        for (int m = 32; m; m >>= 1) ss += __shfl_xor(ss, m);
        if (lane == 0) red[wid] = ss;
        __syncthreads();
        float tot = red[0] + red[1] + red[2] + red[3];
        float rinv = rsqrtf(tot * (1.0f / 1024.0f) + 1e-6f);
        float x0 = hv.x * rinv * wv.x, x1 = hv.y * rinv * wv.y;
        float x2 = hv.z * rinv * wv.z, x3 = hv.w * rinv * wv.w;
        bf16x4 hb = { (bf16)x0, (bf16)x1, (bf16)x2, (bf16)x3 };
        ((bf16x4*)(hn + row * DD))[t] = hb;
        hrow[t*4+0] = x0; hrow[t*4+1] = x1; hrow[t*4+2] = x2; hrow[t*4+3] = x3;
        __syncthreads();
        // qk: col c of [u|v], segment sg of 128 d's
        int c = t & 31, sg = t >> 5;
        const float* hr = hrow + sg * 128;
        float p = 0.0f;
        #pragma unroll 8
        for (int dd = 0; dd < 128; ++dd) p += hr[dd] * (float)Uls[sg * 128 + dd][c];
        qkred[sg][c] = p;
        __syncthreads();
        if (t < 32) {
            float val = 0.0f;
            #pragma unroll
            for (int g = 0; g < 8; ++g) val += qkred[g][t];
            float s2 = val * val;
            s2 += __shfl_xor(s2, 1); s2 += __shfl_xor(s2, 2);
            s2 += __shfl_xor(s2, 4); s2 += __shfl_xor(s2, 8);
            float den = fmaxf(sqrtf(s2), 1e-8f);
            float nvl = val / den;
            if (t < 16) qa[row * RR + t] = nvl * alpha_t;
            else        kk[row * RR + (t - 16)] = nvl;
        }
        __syncthreads();
    }
}

// ---------------- phase A: per-chunk KV increments ----------------
// Inc[bc][r][d] = sum_j gamma_r^(63-j) * k[j,r] * hn[j,d]
__global__ __launch_bounds__(512) void incr_kernel(
    const bf16* __restrict__ hn, const float* __restrict__ kk,
    const float* __restrict__ pp, float* __restrict__ Inc) {
    __shared__ float wjr[64][16];
    int t = threadIdx.x;
    int bc = blockIdx.x;                    // b*16 + c
    size_t row0 = (size_t)bc * 64;          // == b*1024 + c*64
    for (int idx = t; idx < 1024; idx += 512) {
        int j = idx >> 4, r = idx & 15;
        wjr[j][r] = kk[(row0 + j) * RR + r] * pp[PP_GP + r * 72 + (63 - j)];
    }
    __syncthreads();
    int d0 = t * 2;
    float acc0[16], acc1[16];
    #pragma unroll
    for (int r = 0; r < 16; ++r) { acc0[r] = 0.f; acc1[r] = 0.f; }
    for (int j = 0; j < 64; ++j) {
        bf16x2 hv = *(const bf16x2*)(hn + (row0 + j) * DD + d0);
        float x0 = (float)hv[0], x1 = (float)hv[1];
        #pragma unroll
        for (int r = 0; r < 16; ++r) {
            float w = wjr[j][r];
            acc0[r] += w * x0; acc1[r] += w * x1;
        }
    }
    float* outp = Inc + (size_t)bc * 16 * 1024;
    #pragma unroll
    for (int r = 0; r < 16; ++r) {
        float2 o = { acc0[r], acc1[r] };
        *(float2*)&outp[r * 1024 + d0] = o;
    }
}

// ---------------- phase B: sequential chunk-state scan ----------------
__global__ __launch_bounds__(256) void scan_kernel(
    const float* __restrict__ Inc, const float* __restrict__ pp,
    float* __restrict__ Sprev) {
    int gid = blockIdx.x * 256 + threadIdx.x;    // B*R*D = 131072
    int b = gid >> 14, rd = gid & 16383;
    int r = rd >> 10;
    float gd = pp[PP_GP + r * 72 + 64];          // gamma^64
    float s = 0.0f;
    for (int c = 0; c < 16; ++c) {
        size_t idx = ((size_t)(b * 16 + c) << 14) + rd;
        Sprev[idx] = s;
        s = s * gd + Inc[idx];
    }
}

// ---------------- phase C: intra-chunk + state term + conv -> out_pre ----------------
__global__ __launch_bounds__(256) void phasec_kernel(
    const bf16* __restrict__ hn, const float* __restrict__ qa, const float* __restrict__ kk,
    const float* __restrict__ Sprev, const float* __restrict__ pp,
    bf16* __restrict__ outpre) {
    __shared__ float qa_s[64][16], kk_s[64][16];
    __shared__ float gpow[16][65];
    __shared__ float Mco[64][80];
    __shared__ __attribute__((aligned(16))) bf16 X[80][256];
    __shared__ __attribute__((aligned(16))) bf16 P3[3][256];
    __shared__ float kks[4];
    int t = threadIdx.x;
    int bc = blockIdx.x;
    int c = bc & 15;
    int dt = blockIdx.y * 256;
    size_t row0 = (size_t)bc * 64;
    for (int idx = t; idx < 1024; idx += 256) {
        int j = idx >> 4, r = idx & 15;
        qa_s[j][r] = qa[(row0 + j) * RR + r];
        kk_s[j][r] = kk[(row0 + j) * RR + r];
    }
    for (int idx = t; idx < 16 * 65; idx += 256) {
        int r = idx / 65, p = idx - r * 65;
        gpow[r][p] = pp[PP_GP + r * 72 + p];
    }
    for (int idx = t; idx < 64 * 64; idx += 256) {   // hn rows, bf16x4 chunks
        int j = idx >> 6, ch = idx & 63;
        *(bf16x4*)&X[j][ch * 4] = *(const bf16x4*)(hn + (row0 + j) * DD + dt + ch * 4);
    }
    for (int idx = t; idx < 16 * 256; idx += 256) {  // Sprev rows
        int r = idx >> 8, dd = idx & 255;
        X[64 + r][dd] = (bf16)Sprev[((size_t)bc << 14) + r * 1024 + dt + dd];
    }
    for (int idx = t; idx < 3 * 64; idx += 256) {    // 3 previous rows (conv halo)
        int j = idx >> 6, ch = idx & 63;
        bf16x4 val = {};
        if (c > 0) val = *(const bf16x4*)(hn + (row0 - 3 + j) * DD + dt + ch * 4);
        *(bf16x4*)&P3[j][ch * 4] = val;
    }
    if (t < 4) kks[t] = pp[PP_KKER + t];
    __syncthreads();
    // build coefficient matrix M[ii][0..63]=intra, [64..79]=state weights
    for (int idx = t; idx < 64 * 80; idx += 256) {
        int ii = idx / 80, jj = idx - ii * 80;
        float val;
        if (jj < 64) {
            if (jj <= ii) {
                float a = 0.0f;
                #pragma unroll
                for (int r = 0; r < 16; ++r) a += qa_s[ii][r] * kk_s[jj][r] * gpow[r][ii - jj];
                val = a;
            } else val = 0.0f;
        } else {
            int r = jj - 64;
            val = qa_s[ii][r] * gpow[r][ii + 1];
        }
        Mco[ii][jj] = val;
    }
    __syncthreads();
    int g = t >> 6, dd = (t & 63) * 4;
    float acc[16][4] = {};
    for (int jj = 0; jj < 80; ++jj) {
        bf16x4 xv = *(const bf16x4*)&X[jj][dd];
        float x0 = (float)xv[0], x1 = (float)xv[1], x2 = (float)xv[2], x3 = (float)xv[3];
        #pragma unroll
        for (int q = 0; q < 16; ++q) {
            float m = Mco[g * 16 + q][jj];
            acc[q][0] += m * x0; acc[q][1] += m * x1;
            acc[q][2] += m * x2; acc[q][3] += m * x3;
        }
    }
    float k0 = kks[0], k1 = kks[1], k2 = kks[2], k3 = kks[3];
    #pragma unroll
    for (int q = 0; q < 16; ++q) {
        int ii = g * 16 + q;
        const bf16* r0p = &X[ii][dd];
        const bf16* r1p = (ii >= 1) ? &X[ii - 1][dd] : &P3[2][dd];
        const bf16* r2p = (ii >= 2) ? &X[ii - 2][dd] : &P3[ii + 1][dd];
        const bf16* r3p = (ii >= 3) ? &X[ii - 3][dd] : &P3[ii][dd];
        bf16x4 ob;
        #pragma unroll
        for (int e = 0; e < 4; ++e) {
            float v = acc[q][e] + k0 * (float)r0p[e] + k1 * (float)r1p[e]
                                + k2 * (float)r2p[e] + k3 * (float)r3p[e];
            ob[e] = (bf16)v;
        }
        *(bf16x4*)(outpre + (row0 + ii) * DD + dt + dd) = ob;
    }
}

// ---------------- weight conversion ----------------
__global__ void cvt_bf16_kernel(const float* __restrict__ in, bf16* __restrict__ out, int n4) {
    int i = blockIdx.x * 256 + threadIdx.x;
    if (i < n4) {
        float4 v = ((const float4*)in)[i];
        bf16x4 o = { (bf16)v.x, (bf16)v.y, (bf16)v.z, (bf16)v.w };
        ((bf16x4*)out)[i] = o;
    }
}

// in: K x N fp32 row-major  ->  out: N x K bf16 row-major
__global__ __launch_bounds__(256) void trcvt_kernel(
    const float* __restrict__ in, bf16* __restrict__ out, int K, int N) {
    __shared__ float tl[32][33];
    int x0 = blockIdx.x * 32, y0 = blockIdx.y * 32;
    int tx = threadIdx.x & 31, ty = threadIdx.x >> 5;
    #pragma unroll
    for (int i = 0; i < 4; ++i)
        tl[ty + i * 8][tx] = in[(size_t)(y0 + ty + i * 8) * N + x0 + tx];
    __syncthreads();
    #pragma unroll
    for (int i = 0; i < 4; ++i)
        out[(size_t)(x0 + ty + i * 8) * K + y0 + tx] = (bf16)tl[tx][ty + i * 8];
}

// ---------------- rmsnorm2 ----------------
__global__ __launch_bounds__(256) void rms2_kernel(
    const float* __restrict__ h2, const float* __restrict__ nw, bf16* __restrict__ hn2) {
    __shared__ float red[4];
    int t = threadIdx.x;
    size_t row = blockIdx.x;
    float4 hv = ((const float4*)(h2 + row * DD))[t];
    float ss = hv.x*hv.x + hv.y*hv.y + hv.z*hv.z + hv.w*hv.w;
    for (int m = 32; m; m >>= 1) ss += __shfl_xor(ss, m);
    if ((t & 63) == 0) red[t >> 6] = ss;
    __syncthreads();
    float tot = red[0] + red[1] + red[2] + red[3];
    float rinv = rsqrtf(tot * (1.0f / 1024.0f) + 1e-6f);
    float4 wv = ((const float4*)nw)[t];
    bf16x4 o = { (bf16)(hv.x * rinv * wv.x), (bf16)(hv.y * rinv * wv.y),
                 (bf16)(hv.z * rinv * wv.z), (bf16)(hv.w * rinv * wv.w) };
    ((bf16x4*)(hn2 + row * DD))[t] = o;
}

// ---------------- MFMA GEMM: C = A(MxK) @ Bt(NxK)^T, m97-style ----------------
// EPI 0: outf = resid + acc + bias (fp32)    [proj -> h2]
// EPI 1: outb = gelu(acc + bias)   (bf16)    [mlp1 -> hidden]
// EPI 2: outf = resid + acc + bias (fp32)    [mlp2 -> d_out]
template <int EPI>
__global__ __launch_bounds__(256, 2) void gemm_bt_kernel(
    const bf16* __restrict__ A, const bf16* __restrict__ Bt,
    const float* __restrict__ bias, const float* __restrict__ resid,
    float* __restrict__ outf, bf16* __restrict__ outb, int K, int N) {
    __shared__ __attribute__((aligned(16))) bf16 As[128 * 32];
    __shared__ __attribute__((aligned(16))) bf16 Bs[128 * 32];
    int tid = threadIdx.x, lane = tid & 63, wid = tid >> 6;
    int quad = lane >> 4, l16 = lane & 15;
    int m0 = blockIdx.y * 128, n0 = blockIdx.x * 128;
    int wm = (wid >> 1) * 64, wn = (wid & 1) * 64;
    int ci0 = wid * 128 + lane, ci1 = ci0 + 64;
    const bf16* Ab0 = A + (size_t)(m0 + (ci0 >> 2)) * K + (ci0 & 3) * 8;
    const bf16* Ab1 = A + (size_t)(m0 + (ci1 >> 2)) * K + (ci1 & 3) * 8;
    const bf16* Bb0 = Bt + (size_t)(n0 + (ci0 >> 2)) * K + (ci0 & 3) * 8;
    const bf16* Bb1 = Bt + (size_t)(n0 + (ci1 >> 2)) * K + (ci1 & 3) * 8;
    floatx4 acc[4][4] = {};
    for (int kt = 0; kt < K; kt += 32) {
        g2l16(Ab0 + kt, As + ci0 * 8);
        g2l16(Ab1 + kt, As + ci1 * 8);
        g2l16(Bb0 + kt, Bs + ci0 * 8);
        g2l16(Bb1 + kt, Bs + ci1 * 8);
        __syncthreads();
        bf16x8 af[4], bfr[4];
        #pragma unroll
        for (int tm = 0; tm < 4; ++tm)
            af[tm] = *(const bf16x8*)(As + (wm + tm * 16 + l16) * 32 + quad * 8);
        #pragma unroll
        for (int tn = 0; tn < 4; ++tn)
            bfr[tn] = *(const bf16x8*)(Bs + (wn + tn * 16 + l16) * 32 + quad * 8);
        #pragma unroll
        for (int tm = 0; tm < 4; ++tm)
            #pragma unroll
            for (int tn = 0; tn < 4; ++tn)
                acc[tm][tn] = __builtin_amdgcn_mfma_f32_16x16x32_bf16(
                    af[tm], bfr[tn], acc[tm][tn], 0, 0, 0);
        __syncthreads();
    }
    #pragma unroll
    for (int tn = 0; tn < 4; ++tn) {
        int gn = n0 + wn + tn * 16 + l16;
        float bs = bias[gn];
        #pragma unroll
        for (int tm = 0; tm < 4; ++tm) {
            #pragma unroll
            for (int r = 0; r < 4; ++r) {
                size_t gm = (size_t)m0 + wm + tm * 16 + quad * 4 + r;
                float v = acc[tm][tn][r] + bs;
                if (EPI == 1) {
                    outb[gm * N + gn] = (bf16)gelu_f(v);
                } else {
                    v += resid[gm * N + gn];
                    outf[gm * N + gn] = v;
                }
            }
        }
    }
}

// ---------------- launch ----------------
extern "C" void kernel_launch(void* const* d_in, const int* in_sizes, int n_in,
                              void* d_out, int out_size, void* d_ws, size_t ws_size,
                              hipStream_t stream) {
    const float* h           = (const float*)d_in[0];
    const float* u           = (const float*)d_in[1];
    const float* v           = (const float*)d_in[2];
    const float* decay_logit = (const float*)d_in[3];
    const float* alpha_logit = (const float*)d_in[4];
    const float* gate_logit  = (const float*)d_in[5];
    const float* kbase       = (const float*)d_in[6];
    const float* proj_w      = (const float*)d_in[7];
    const float* proj_b      = (const float*)d_in[8];
    const float* norm1_w     = (const float*)d_in[9];
    const float* norm2_w     = (const float*)d_in[10];
    const float* mlp_w1      = (const float*)d_in[11];
    const float* mlp_b1      = (const float*)d_in[12];
    const float* mlp_w2      = (const float*)d_in[13];
    const float* mlp_b2      = (const float*)d_in[14];
    float* out = (float*)d_out;

    char* wsb = (char*)d_ws;
    size_t off = 0;
    auto alloc = [&](size_t bytes) -> void* {
        void* p = wsb + off;
        off += (bytes + 255) & ~(size_t)255;
        return p;
    };
    float* pp     = (float*)alloc(PP_FLOATS * 4);
    bf16*  hn     = (bf16*) alloc((size_t)8192 * 1024 * 2);
    float* qa     = (float*)alloc((size_t)8192 * 16 * 4);
    float* kk     = (float*)alloc((size_t)8192 * 16 * 4);
    float* Inc    = (float*)alloc((size_t)128 * 16 * 1024 * 4);
    float* Sprev  = (float*)alloc((size_t)128 * 16 * 1024 * 4);
    bf16*  outpre = (bf16*) alloc((size_t)8192 * 1024 * 2);
    float* h2     = (float*)alloc((size_t)8192 * 1024 * 4);
    bf16*  hidden = (bf16*) alloc((size_t)8192 * 4096 * 2);
    bf16*  Wp     = (bf16*) alloc((size_t)1024 * 1024 * 2);
    bf16*  W1t    = (bf16*) alloc((size_t)4096 * 1024 * 2);
    bf16*  W2t    = (bf16*) alloc((size_t)1024 * 4096 * 2);
    bf16*  hn2 = hn;   // hn dead after phasec; reuse for rmsnorm2 output

    params_kernel<<<1, 64, 0, stream>>>(decay_logit, alpha_logit, gate_logit, kbase, pp);
    cvt_bf16_kernel<<<1024, 256, 0, stream>>>(proj_w, Wp, 1024 * 1024 / 4);
    trcvt_kernel<<<dim3(4096 / 32, 1024 / 32), 256, 0, stream>>>(mlp_w1, W1t, 1024, 4096);
    trcvt_kernel<<<dim3(1024 / 32, 4096 / 32), 256, 0, stream>>>(mlp_w2, W2t, 4096, 1024);
    rmsqk_kernel<<<512, 256, 0, stream>>>(h, u, v, norm1_w, pp, hn, qa, kk);
    incr_kernel<<<128, 512, 0, stream>>>(hn, kk, pp, Inc);
    scan_kernel<<<512, 256, 0, stream>>>(Inc, pp, Sprev);
    phasec_kernel<<<dim3(128, 4), 256, 0, stream>>>(hn, qa, kk, Sprev, pp, outpre);
    gemm_bt_kernel<0><<<dim3(8, 64), 256, 0, stream>>>(outpre, Wp, proj_b, h, h2, nullptr, 1024, 1024);
    rms2_kernel<<<8192, 256, 0, stream>>>(h2, norm2_w, hn2);
    gemm_bt_kernel<1><<<dim3(32, 64), 256, 0, stream>>>(hn2, W1t, mlp_b1, nullptr, nullptr, hidden, 1024, 4096);
    gemm_bt_kernel<2><<<dim3(8, 64), 256, 0, stream>>>(hidden, W2t, mlp_b2, h2, out, nullptr, 4096, 1024);
}

// Round 2
// 431.591 us; speedup vs baseline: 1.1142x; 1.1142x over previous
//
#include <hip/hip_runtime.h>
#include <hip/hip_bf16.h>
#include <cstdint>
#include <cstddef>

// ---------------- types ----------------
typedef __bf16 bf16;
typedef __bf16 bf16x2 __attribute__((ext_vector_type(2)));
typedef __bf16 bf16x4 __attribute__((ext_vector_type(4)));
typedef __bf16 bf16x8 __attribute__((ext_vector_type(8)));
typedef float  floatx4 __attribute__((ext_vector_type(4)));

// problem constants
#define BB 8
#define SS 1024
#define DD 1024
#define RR 16
#define CHK 64
#define NCH 16

// params buffer layout (floats)
#define PP_ALPHA 0
#define PP_GAMMA 16
#define PP_GP    32           // 16*72: gamma^0..gamma^71 per r
#define PP_KKER  (32 + 16*72)
#define PP_FLOATS 2048

__device__ __forceinline__ float sigmoidf_(float x) { return 1.0f / (1.0f + __expf(-x)); }

__device__ __forceinline__ float gelu_f(float x) {
    float u = 0.7978845608028654f * (x + 0.044715f * x * x * x);
    float t = 1.0f - 2.0f / (__expf(2.0f * u) + 1.0f);
    return 0.5f * x * (1.0f + t);
}

__device__ __forceinline__ void g2l16(const bf16* g, bf16* l) {
    __builtin_amdgcn_global_load_lds(
        (const __attribute__((address_space(1))) void*)g,
        (__attribute__((address_space(3))) void*)l, 16, 0, 0);
}

// ---------------- scalar params ----------------
__global__ void params_kernel(const float* __restrict__ decay_logit,
                              const float* __restrict__ alpha_logit,
                              const float* __restrict__ gate_logit,
                              const float* __restrict__ kbase,
                              float* __restrict__ pp) {
    int t = threadIdx.x;
    if (t < 16) {
        pp[PP_ALPHA + t] = sigmoidf_(alpha_logit[t]);
        float g = sigmoidf_(decay_logit[t]);
        g = fminf(fmaxf(g, 0.15f), 1.0f);
        pp[PP_GAMMA + t] = g;
        float acc = 1.0f;
        for (int p = 0; p < 72; ++p) { pp[PP_GP + t * 72 + p] = acc; acc *= g; }
    }
    if (t >= 16 && t < 20) {
        float gate = sigmoidf_(gate_logit[0]);
        pp[PP_KKER + (t - 16)] = gate * kbase[t - 16];
    }
}

// ---------------- [u|v] -> transposed bf16 (32 x 1024) ----------------
__global__ void uvt_kernel(const float* __restrict__ u, const float* __restrict__ v,
                           bf16* __restrict__ Ut) {
    int c = blockIdx.x;                 // 0..31
    const float* src = (c < 16) ? u : v;
    int cc = c & 15;
    for (int d = threadIdx.x; d < 1024; d += 256)
        Ut[c * 1024 + d] = (bf16)src[d * 16 + cc];
}

// ---------------- rmsnorm1 + qk projection + l2norm ----------------
__global__ __launch_bounds__(256) void rmsqk_kernel(
    const float* __restrict__ h, const bf16* __restrict__ Ut,
    const float* __restrict__ nw, const float* __restrict__ pp,
    bf16* __restrict__ hn, float* __restrict__ qa, float* __restrict__ kk) {
    __shared__ __attribute__((aligned(16))) bf16 Ult[32][1032];
    __shared__ __attribute__((aligned(16))) float hrow[1024];
    __shared__ float red[4];
    __shared__ float qkred[8][32];
    int t = threadIdx.x;
    for (int i = t; i < 32 * 128; i += 256) {
        int c = i >> 7, ch = i & 127;
        *(bf16x8*)&Ult[c][ch * 8] = *(const bf16x8*)(Ut + c * 1024 + ch * 8);
    }
    int lane = t & 63, wid = t >> 6;
    float4 wv = ((const float4*)nw)[t];
    float alpha_t = (t < 16) ? pp[PP_ALPHA + t] : 0.0f;
    size_t row0 = (size_t)blockIdx.x * 16;
    __syncthreads();
    for (int rr = 0; rr < 16; ++rr) {
        size_t row = row0 + rr;
        float4 hv = ((const float4*)(h + row * DD))[t];
        float ss = hv.x*hv.x + hv.y*hv.y + hv.z*hv.z + hv.w*hv.w;
        for (int m = 32; m; m >>= 1) ss += __shfl_xor(ss, m);
        if (lane == 0) red[wid] = ss;
        __syncthreads();
        float tot = red[0] + red[1] + red[2] + red[3];
        float rinv = rsqrtf(tot * (1.0f / 1024.0f) + 1e-6f);
        float x0 = hv.x * rinv * wv.x, x1 = hv.y * rinv * wv.y;
        float x2 = hv.z * rinv * wv.z, x3 = hv.w * rinv * wv.w;
        bf16x4 hb = { (bf16)x0, (bf16)x1, (bf16)x2, (bf16)x3 };
        ((bf16x4*)(hn + row * DD))[t] = hb;
        hrow[t*4+0] = x0; hrow[t*4+1] = x1; hrow[t*4+2] = x2; hrow[t*4+3] = x3;
        __syncthreads();
        int c = t & 31, sg = t >> 5;
        const bf16* up = &Ult[c][sg * 128];
        const float* hp = &hrow[sg * 128];
        float p = 0.0f;
        #pragma unroll
        for (int k8 = 0; k8 < 16; ++k8) {
            bf16x8 u8 = *(const bf16x8*)(up + k8 * 8);
            float4 h0 = *(const float4*)(hp + k8 * 8);
            float4 h1 = *(const float4*)(hp + k8 * 8 + 4);
            p += h0.x*(float)u8[0] + h0.y*(float)u8[1] + h0.z*(float)u8[2] + h0.w*(float)u8[3]
               + h1.x*(float)u8[4] + h1.y*(float)u8[5] + h1.z*(float)u8[6] + h1.w*(float)u8[7];
        }
        qkred[sg][c] = p;
        __syncthreads();
        if (t < 32) {
            float val = 0.0f;
            #pragma unroll
            for (int g = 0; g < 8; ++g) val += qkred[g][t];
            float s2 = val * val;
            s2 += __shfl_xor(s2, 1); s2 += __shfl_xor(s2, 2);
            s2 += __shfl_xor(s2, 4); s2 += __shfl_xor(s2, 8);
            float den = fmaxf(sqrtf(s2), 1e-8f);
            float nvl = val / den;
            if (t < 16) qa[row * RR + t] = nvl * alpha_t;
            else        kk[row * RR + (t - 16)] = nvl;
        }
        __syncthreads();
    }
}

// ---------------- phase A: per-chunk KV increments ----------------
__global__ __launch_bounds__(256) void incr_kernel(
    const bf16* __restrict__ hn, const float* __restrict__ kk,
    const float* __restrict__ pp, float* __restrict__ Inc) {
    __shared__ __attribute__((aligned(16))) float wjr[64][16];
    int t = threadIdx.x;
    int bc = blockIdx.x;
    int d0 = blockIdx.y * 256 + t;
    size_t row0 = (size_t)bc * 64;
    for (int idx = t; idx < 1024; idx += 256) {
        int j = idx >> 4, r = idx & 15;
        wjr[j][r] = kk[(row0 + j) * RR + r] * pp[PP_GP + r * 72 + (63 - j)];
    }
    __syncthreads();
    float acc[16] = {};
    for (int j = 0; j < 64; ++j) {
        float x = (float)hn[(row0 + j) * DD + d0];
        const float4* w4 = (const float4*)wjr[j];
        float4 w0 = w4[0], w1 = w4[1], w2 = w4[2], w3 = w4[3];
        acc[0]  += w0.x * x; acc[1]  += w0.y * x; acc[2]  += w0.z * x; acc[3]  += w0.w * x;
        acc[4]  += w1.x * x; acc[5]  += w1.y * x; acc[6]  += w1.z * x; acc[7]  += w1.w * x;
        acc[8]  += w2.x * x; acc[9]  += w2.y * x; acc[10] += w2.z * x; acc[11] += w2.w * x;
        acc[12] += w3.x * x; acc[13] += w3.y * x; acc[14] += w3.z * x; acc[15] += w3.w * x;
    }
    float* outp = Inc + (size_t)bc * 16 * 1024 + d0;
    #pragma unroll
    for (int r = 0; r < 16; ++r) outp[r * 1024] = acc[r];
}

// ---------------- phase B: sequential chunk-state scan ----------------
__global__ __launch_bounds__(256) void scan_kernel(
    const float* __restrict__ Inc, const float* __restrict__ pp,
    float* __restrict__ Sprev) {
    int gid = blockIdx.x * 256 + threadIdx.x;
    int b = gid >> 14, rd = gid & 16383;
    int r = rd >> 10;
    float gd = pp[PP_GP + r * 72 + 64];
    float s = 0.0f;
    for (int c = 0; c < 16; ++c) {
        size_t idx = ((size_t)(b * 16 + c) << 14) + rd;
        Sprev[idx] = s;
        s = s * gd + Inc[idx];
    }
}

// ---------------- phase C: intra-chunk + state term + conv ----------------
__global__ __launch_bounds__(256) void phasec_kernel(
    const bf16* __restrict__ hn, const float* __restrict__ qa, const float* __restrict__ kk,
    const float* __restrict__ Sprev, const float* __restrict__ pp,
    bf16* __restrict__ outpre) {
    __shared__ __attribute__((aligned(16))) float qa_s[64][16];
    __shared__ __attribute__((aligned(16))) float kk_s[64][16];
    __shared__ __attribute__((aligned(16))) float gpt[65][16];   // gpt[p][r]
    __shared__ __attribute__((aligned(16))) float Mco[64][80];
    __shared__ __attribute__((aligned(16))) bf16 X[80][256];
    __shared__ __attribute__((aligned(16))) bf16 P3[3][256];
    __shared__ float kks[4];
    int t = threadIdx.x;
    int bc = blockIdx.x;
    int c = bc & 15;
    int dt = blockIdx.y * 256;
    size_t row0 = (size_t)bc * 64;
    for (int idx = t; idx < 1024; idx += 256) {
        int j = idx >> 4, r = idx & 15;
        qa_s[j][r] = qa[(row0 + j) * RR + r];
        kk_s[j][r] = kk[(row0 + j) * RR + r];
    }
    for (int idx = t; idx < 16 * 65; idx += 256) {
        int p = idx >> 4, r = idx & 15;
        gpt[p][r] = pp[PP_GP + r * 72 + p];
    }
    for (int idx = t; idx < 64 * 64; idx += 256) {
        int j = idx >> 6, ch = idx & 63;
        *(bf16x4*)&X[j][ch * 4] = *(const bf16x4*)(hn + (row0 + j) * DD + dt + ch * 4);
    }
    for (int idx = t; idx < 16 * 256; idx += 256) {
        int r = idx >> 8, dd = idx & 255;
        X[64 + r][dd] = (bf16)Sprev[((size_t)bc << 14) + r * 1024 + dt + dd];
    }
    for (int idx = t; idx < 3 * 64; idx += 256) {
        int j = idx >> 6, ch = idx & 63;
        bf16x4 val = {};
        if (c > 0) val = *(const bf16x4*)(hn + (row0 - 3 + j) * DD + dt + ch * 4);
        *(bf16x4*)&P3[j][ch * 4] = val;
    }
    if (t < 4) kks[t] = pp[PP_KKER + t];
    __syncthreads();
    // coefficient matrix, r-vectorized (float4 LDS reads)
    for (int idx = t; idx < 64 * 80; idx += 256) {
        int ii = idx / 80, jj = idx - ii * 80;
        float val;
        if (jj < 64) {
            if (jj <= ii) {
                const float4* qa4 = (const float4*)qa_s[ii];
                const float4* kk4 = (const float4*)kk_s[jj];
                const float4* gp4 = (const float4*)gpt[ii - jj];
                float s = 0.0f;
                #pragma unroll
                for (int x = 0; x < 4; ++x) {
                    float4 qv = qa4[x], kv = kk4[x], gv = gp4[x];
                    s += qv.x*kv.x*gv.x + qv.y*kv.y*gv.y + qv.z*kv.z*gv.z + qv.w*kv.w*gv.w;
                }
                val = s;
            } else val = 0.0f;
        } else {
            int r = jj - 64;
            val = qa_s[ii][r] * gpt[ii + 1][r];
        }
        Mco[ii][jj] = val;
    }
    __syncthreads();
    int g = t >> 6, dd4 = (t & 63) * 4;
    const float* mbase = &Mco[g * 16][0];
    float acc[16][4] = {};
    for (int jc = 0; jc < 20; ++jc) {
        float xv[4][4];
        #pragma unroll
        for (int e = 0; e < 4; ++e) {
            bf16x4 x = *(const bf16x4*)&X[jc * 4 + e][dd4];
            xv[e][0] = (float)x[0]; xv[e][1] = (float)x[1];
            xv[e][2] = (float)x[2]; xv[e][3] = (float)x[3];
        }
        #pragma unroll
        for (int q = 0; q < 16; ++q) {
            float4 m = *(const float4*)(mbase + q * 80 + jc * 4);
            #pragma unroll
            for (int e = 0; e < 4; ++e)
                acc[q][e] += m.x * xv[0][e] + m.y * xv[1][e] + m.z * xv[2][e] + m.w * xv[3][e];
        }
    }
    float k0 = kks[0], k1 = kks[1], k2 = kks[2], k3 = kks[3];
    #pragma unroll
    for (int q = 0; q < 16; ++q) {
        int ii = g * 16 + q;
        const bf16* r0p = &X[ii][dd4];
        const bf16* r1p = (ii >= 1) ? &X[ii - 1][dd4] : &P3[2][dd4];
        const bf16* r2p = (ii >= 2) ? &X[ii - 2][dd4] : &P3[ii + 1][dd4];
        const bf16* r3p = (ii >= 3) ? &X[ii - 3][dd4] : &P3[ii][dd4];
        bf16x4 ob;
        #pragma unroll
        for (int e = 0; e < 4; ++e) {
            float vv = acc[q][e] + k0 * (float)r0p[e] + k1 * (float)r1p[e]
                                 + k2 * (float)r2p[e] + k3 * (float)r3p[e];
            ob[e] = (bf16)vv;
        }
        *(bf16x4*)(outpre + (row0 + ii) * DD + dt + dd4) = ob;
    }
}

// ---------------- weight conversion ----------------
__global__ void cvt_bf16_kernel(const float* __restrict__ in, bf16* __restrict__ out, int n4) {
    int i = blockIdx.x * 256 + threadIdx.x;
    if (i < n4) {
        float4 v = ((const float4*)in)[i];
        bf16x4 o = { (bf16)v.x, (bf16)v.y, (bf16)v.z, (bf16)v.w };
        ((bf16x4*)out)[i] = o;
    }
}

__global__ __launch_bounds__(256) void trcvt_kernel(
    const float* __restrict__ in, bf16* __restrict__ out, int K, int N) {
    __shared__ float tl[32][33];
    int x0 = blockIdx.x * 32, y0 = blockIdx.y * 32;
    int tx = threadIdx.x & 31, ty = threadIdx.x >> 5;
    #pragma unroll
    for (int i = 0; i < 4; ++i)
        tl[ty + i * 8][tx] = in[(size_t)(y0 + ty + i * 8) * N + x0 + tx];
    __syncthreads();
    #pragma unroll
    for (int i = 0; i < 4; ++i)
        out[(size_t)(x0 + ty + i * 8) * K + y0 + tx] = (bf16)tl[tx][ty + i * 8];
}

// ---------------- rmsnorm2 ----------------
__global__ __launch_bounds__(256) void rms2_kernel(
    const float* __restrict__ h2, const float* __restrict__ nw, bf16* __restrict__ hn2) {
    __shared__ float red[4];
    int t = threadIdx.x;
    size_t row = blockIdx.x;
    float4 hv = ((const float4*)(h2 + row * DD))[t];
    float ss = hv.x*hv.x + hv.y*hv.y + hv.z*hv.z + hv.w*hv.w;
    for (int m = 32; m; m >>= 1) ss += __shfl_xor(ss, m);
    if ((t & 63) == 0) red[t >> 6] = ss;
    __syncthreads();
    float tot = red[0] + red[1] + red[2] + red[3];
    float rinv = rsqrtf(tot * (1.0f / 1024.0f) + 1e-6f);
    float4 wv = ((const float4*)nw)[t];
    bf16x4 o = { (bf16)(hv.x * rinv * wv.x), (bf16)(hv.y * rinv * wv.y),
                 (bf16)(hv.z * rinv * wv.z), (bf16)(hv.w * rinv * wv.w) };
    ((bf16x4*)(hn2 + row * DD))[t] = o;
}

// ---------------- MFMA GEMM, BK=64, XOR-swizzled LDS, XCD-cohort blocks ----
// grid must be (nx, 64). C = A(8192xK) @ Bt(NxK)^T
template <int EPI>
__global__ __launch_bounds__(256, 2) void gemm_bt_kernel(
    const bf16* __restrict__ A, const bf16* __restrict__ Bt,
    const float* __restrict__ bias, const float* __restrict__ resid,
    float* __restrict__ outf, bf16* __restrict__ outb, int K, int N) {
    __shared__ __attribute__((aligned(16))) bf16 As[128 * 64];
    __shared__ __attribute__((aligned(16))) bf16 Bs[128 * 64];
    int tid = threadIdx.x, lane = tid & 63, wid = tid >> 6;
    int quad = lane >> 4, l16 = lane & 15;
    // XCD cohort swizzle: 8 consecutive-linear blocks (one per XCD) share n,
    // each XCD's 64-block set = 8 m-tiles x all n-tiles (slab-streams A via L2)
    int lb = blockIdx.y * gridDim.x + blockIdx.x;
    int xcd = lb & 7, q = lb >> 3;
    int m0 = (xcd * 8 + (q & 7)) * 128;
    int n0 = (q >> 3) * 128;
    int wm = (wid >> 1) * 64, wn = (wid & 1) * 64;
    // staging: 1024 slots/matrix, 16B each; slot s holds row s>>3, chunk (s&7)^(row&7)
    const bf16* Ap[4]; const bf16* Bp[4]; int lo[4];
    #pragma unroll
    for (int j = 0; j < 4; ++j) {
        int s = j * 256 + tid;
        int row = s >> 3, cc = s & 7;
        int gc = cc ^ (row & 7);
        Ap[j] = A  + (size_t)(m0 + row) * K + gc * 8;
        Bp[j] = Bt + (size_t)(n0 + row) * K + gc * 8;
        lo[j] = s * 8;
    }
    floatx4 acc[4][4] = {};
    for (int kt = 0; kt < K; kt += 64) {
        #pragma unroll
        for (int j = 0; j < 4; ++j) {
            g2l16(Ap[j] + kt, As + lo[j]);
            g2l16(Bp[j] + kt, Bs + lo[j]);
        }
        __syncthreads();
        #pragma unroll
        for (int ks = 0; ks < 2; ++ks) {
            bf16x8 af[4], bfr[4];
            #pragma unroll
            for (int tm = 0; tm < 4; ++tm) {
                int row = wm + tm * 16 + l16;
                int cc = (ks * 4 + quad) ^ (row & 7);
                af[tm] = *(const bf16x8*)(As + row * 64 + cc * 8);
            }
            #pragma unroll
            for (int tn = 0; tn < 4; ++tn) {
                int row = wn + tn * 16 + l16;
                int cc = (ks * 4 + quad) ^ (row & 7);
                bfr[tn] = *(const bf16x8*)(Bs + row * 64 + cc * 8);
            }
            #pragma unroll
            for (int tm = 0; tm < 4; ++tm)
                #pragma unroll
                for (int tn = 0; tn < 4; ++tn)
                    acc[tm][tn] = __builtin_amdgcn_mfma_f32_16x16x32_bf16(
                        af[tm], bfr[tn], acc[tm][tn], 0, 0, 0);
        }
        __syncthreads();
    }
    #pragma unroll
    for (int tn = 0; tn < 4; ++tn) {
        int gn = n0 + wn + tn * 16 + l16;
        float bs = bias[gn];
        #pragma unroll
        for (int tm = 0; tm < 4; ++tm) {
            #pragma unroll
            for (int r = 0; r < 4; ++r) {
                size_t gm = (size_t)m0 + wm + tm * 16 + quad * 4 + r;
                float v = acc[tm][tn][r] + bs;
                if (EPI == 1) {
                    outb[gm * N + gn] = (bf16)gelu_f(v);
                } else {
                    v += resid[gm * N + gn];
                    outf[gm * N + gn] = v;
                }
            }
        }
    }
}

// ---------------- launch ----------------
extern "C" void kernel_launch(void* const* d_in, const int* in_sizes, int n_in,
                              void* d_out, int out_size, void* d_ws, size_t ws_size,
                              hipStream_t stream) {
    const float* h           = (const float*)d_in[0];
    const float* u           = (const float*)d_in[1];
    const float* v           = (const float*)d_in[2];
    const float* decay_logit = (const float*)d_in[3];
    const float* alpha_logit = (const float*)d_in[4];
    const float* gate_logit  = (const float*)d_in[5];
    const float* kbase       = (const float*)d_in[6];
    const float* proj_w      = (const float*)d_in[7];
    const float* proj_b      = (const float*)d_in[8];
    const float* norm1_w     = (const float*)d_in[9];
    const float* norm2_w     = (const float*)d_in[10];
    const float* mlp_w1      = (const float*)d_in[11];
    const float* mlp_b1      = (const float*)d_in[12];
    const float* mlp_w2      = (const float*)d_in[13];
    const float* mlp_b2      = (const float*)d_in[14];
    float* out = (float*)d_out;

    char* wsb = (char*)d_ws;
    size_t off = 0;
    auto alloc = [&](size_t bytes) -> void* {
        void* p = wsb + off;
        off += (bytes + 255) & ~(size_t)255;
        return p;
    };
    float* pp     = (float*)alloc(PP_FLOATS * 4);
    bf16*  Ut     = (bf16*) alloc((size_t)32 * 1024 * 2);
    bf16*  hn     = (bf16*) alloc((size_t)8192 * 1024 * 2);
    float* qa     = (float*)alloc((size_t)8192 * 16 * 4);
    float* kk     = (float*)alloc((size_t)8192 * 16 * 4);
    float* Inc    = (float*)alloc((size_t)128 * 16 * 1024 * 4);
    float* Sprev  = (float*)alloc((size_t)128 * 16 * 1024 * 4);
    bf16*  outpre = (bf16*) alloc((size_t)8192 * 1024 * 2);
    float* h2     = (float*)alloc((size_t)8192 * 1024 * 4);
    bf16*  hidden = (bf16*) alloc((size_t)8192 * 4096 * 2);
    bf16*  Wp     = (bf16*) alloc((size_t)1024 * 1024 * 2);
    bf16*  W1t    = (bf16*) alloc((size_t)4096 * 1024 * 2);
    bf16*  W2t    = (bf16*) alloc((size_t)1024 * 4096 * 2);
    bf16*  hn2 = hn;   // hn dead after phasec

    params_kernel<<<1, 64, 0, stream>>>(decay_logit, alpha_logit, gate_logit, kbase, pp);
    uvt_kernel<<<32, 256, 0, stream>>>(u, v, Ut);
    cvt_bf16_kernel<<<1024, 256, 0, stream>>>(proj_w, Wp, 1024 * 1024 / 4);
    trcvt_kernel<<<dim3(4096 / 32, 1024 / 32), 256, 0, stream>>>(mlp_w1, W1t, 1024, 4096);
    trcvt_kernel<<<dim3(1024 / 32, 4096 / 32), 256, 0, stream>>>(mlp_w2, W2t, 4096, 1024);
    rmsqk_kernel<<<512, 256, 0, stream>>>(h, Ut, norm1_w, pp, hn, qa, kk);
    incr_kernel<<<dim3(128, 4), 256, 0, stream>>>(hn, kk, pp, Inc);
    scan_kernel<<<512, 256, 0, stream>>>(Inc, pp, Sprev);
    phasec_kernel<<<dim3(128, 4), 256, 0, stream>>>(hn, qa, kk, Sprev, pp, outpre);
    gemm_bt_kernel<0><<<dim3(8, 64), 256, 0, stream>>>(outpre, Wp, proj_b, h, h2, nullptr, 1024, 1024);
    rms2_kernel<<<8192, 256, 0, stream>>>(h2, norm2_w, hn2);
    gemm_bt_kernel<1><<<dim3(32, 64), 256, 0, stream>>>(hn2, W1t, mlp_b1, nullptr, nullptr, hidden, 1024, 4096);
    gemm_bt_kernel<2><<<dim3(8, 64), 256, 0, stream>>>(hidden, W2t, mlp_b2, h2, out, nullptr, 4096, 1024);
}

// Round 3
// 394.113 us; speedup vs baseline: 1.2201x; 1.0951x over previous
//
#include <hip/hip_runtime.h>
#include <hip/hip_bf16.h>
#include <cstdint>
#include <cstddef>

// ---------------- types ----------------
typedef __bf16 bf16;
typedef __bf16 bf16x2 __attribute__((ext_vector_type(2)));
typedef __bf16 bf16x4 __attribute__((ext_vector_type(4)));
typedef __bf16 bf16x8 __attribute__((ext_vector_type(8)));
typedef float  floatx4 __attribute__((ext_vector_type(4)));

// problem constants
#define BB 8
#define SS 1024
#define DD 1024
#define RR 16
#define CHK 64
#define NCH 16

// params buffer layout (floats)
#define PP_ALPHA 0
#define PP_GAMMA 16
#define PP_GP    32           // 16*72: gamma^0..gamma^71 per r
#define PP_KKER  (32 + 16*72)
#define PP_FLOATS 2048

__device__ __forceinline__ float sigmoidf_(float x) { return 1.0f / (1.0f + __expf(-x)); }

__device__ __forceinline__ float gelu_f(float x) {
    float u = 0.7978845608028654f * (x + 0.044715f * x * x * x);
    float t = 1.0f - 2.0f / (__expf(2.0f * u) + 1.0f);
    return 0.5f * x * (1.0f + t);
}

__device__ __forceinline__ void g2l16(const bf16* g, bf16* l) {
    __builtin_amdgcn_global_load_lds(
        (const __attribute__((address_space(1))) void*)g,
        (__attribute__((address_space(3))) void*)l, 16, 0, 0);
}

// ---------------- scalar params ----------------
__global__ void params_kernel(const float* __restrict__ decay_logit,
                              const float* __restrict__ alpha_logit,
                              const float* __restrict__ gate_logit,
                              const float* __restrict__ kbase,
                              float* __restrict__ pp) {
    int t = threadIdx.x;
    if (t < 16) {
        pp[PP_ALPHA + t] = sigmoidf_(alpha_logit[t]);
        float g = sigmoidf_(decay_logit[t]);
        g = fminf(fmaxf(g, 0.15f), 1.0f);
        pp[PP_GAMMA + t] = g;
        float acc = 1.0f;
        for (int p = 0; p < 72; ++p) { pp[PP_GP + t * 72 + p] = acc; acc *= g; }
    }
    if (t >= 16 && t < 20) {
        float gate = sigmoidf_(gate_logit[0]);
        pp[PP_KKER + (t - 16)] = gate * kbase[t - 16];
    }
}

// ---------------- [u|v] -> transposed bf16 (32 x 1024) ----------------
__global__ void uvt_kernel(const float* __restrict__ u, const float* __restrict__ v,
                           bf16* __restrict__ Ut) {
    int c = blockIdx.x;                 // 0..31
    const float* src = (c < 16) ? u : v;
    int cc = c & 15;
    for (int d = threadIdx.x; d < 1024; d += 256)
        Ut[c * 1024 + d] = (bf16)src[d * 16 + cc];
}

// ---------------- generic rmsnorm row kernel (fp32 in, bf16 out) ------------
__global__ __launch_bounds__(256) void rmsrow_kernel(
    const float* __restrict__ x, const float* __restrict__ nw, bf16* __restrict__ y) {
    __shared__ float red[4];
    int t = threadIdx.x;
    size_t row = blockIdx.x;
    float4 hv = ((const float4*)(x + row * DD))[t];
    float ss = hv.x*hv.x + hv.y*hv.y + hv.z*hv.z + hv.w*hv.w;
    for (int m = 32; m; m >>= 1) ss += __shfl_xor(ss, m);
    if ((t & 63) == 0) red[t >> 6] = ss;
    __syncthreads();
    float tot = red[0] + red[1] + red[2] + red[3];
    float rinv = rsqrtf(tot * (1.0f / 1024.0f) + 1e-6f);
    float4 wv = ((const float4*)nw)[t];
    bf16x4 o = { (bf16)(hv.x * rinv * wv.x), (bf16)(hv.y * rinv * wv.y),
                 (bf16)(hv.z * rinv * wv.z), (bf16)(hv.w * rinv * wv.w) };
    ((bf16x4*)(y + row * DD))[t] = o;
}

// ---------------- qk projection + l2norm via MFMA ----------------
// hn(8192x1024) @ Ut(32x1024)^T -> per-row l2norm over 16-col halves -> qa, kk
__global__ __launch_bounds__(256) void qk_kernel(
    const bf16* __restrict__ hn, const bf16* __restrict__ Ut,
    const float* __restrict__ pp, float* __restrict__ qa, float* __restrict__ kk) {
    __shared__ __attribute__((aligned(16))) bf16 As[128 * 64];
    __shared__ __attribute__((aligned(16))) bf16 Bs[32 * 64];
    int tid = threadIdx.x, lane = tid & 63, wid = tid >> 6;
    int quad = lane >> 4, l16 = lane & 15;
    int m0 = blockIdx.x * 128;
    int wm = wid * 32;
    // A staging: 1024 slots
    const bf16* Ap[4]; int lo[4];
    #pragma unroll
    for (int j = 0; j < 4; ++j) {
        int s = j * 256 + tid;
        int row = s >> 3, cc = s & 7;
        int gc = cc ^ (row & 7);
        Ap[j] = hn + (size_t)(m0 + row) * DD + gc * 8;
        lo[j] = s * 8;
    }
    // B staging: 256 slots (32 rows x 8 chunks)
    int bs_row = tid >> 3, bs_cc = tid & 7;
    int bs_gc = bs_cc ^ (bs_row & 7);
    const bf16* Bp = Ut + (size_t)bs_row * DD + bs_gc * 8;
    int blo = tid * 8;
    floatx4 acc[2][2] = {};
    for (int kt = 0; kt < 1024; kt += 64) {
        #pragma unroll
        for (int j = 0; j < 4; ++j) g2l16(Ap[j] + kt, As + lo[j]);
        g2l16(Bp + kt, Bs + blo);
        __syncthreads();
        #pragma unroll
        for (int ks = 0; ks < 2; ++ks) {
            bf16x8 af[2], bfr[2];
            #pragma unroll
            for (int tm = 0; tm < 2; ++tm) {
                int row = wm + tm * 16 + l16;
                int cc = (ks * 4 + quad) ^ (row & 7);
                af[tm] = *(const bf16x8*)(As + row * 64 + cc * 8);
            }
            #pragma unroll
            for (int tn = 0; tn < 2; ++tn) {
                int row = tn * 16 + l16;
                int cc = (ks * 4 + quad) ^ (row & 7);
                bfr[tn] = *(const bf16x8*)(Bs + row * 64 + cc * 8);
            }
            #pragma unroll
            for (int tm = 0; tm < 2; ++tm)
                #pragma unroll
                for (int tn = 0; tn < 2; ++tn)
                    acc[tm][tn] = __builtin_amdgcn_mfma_f32_16x16x32_bf16(
                        af[tm], bfr[tn], acc[tm][tn], 0, 0, 0);
        }
        __syncthreads();
    }
    float alf = pp[PP_ALPHA + l16];
    #pragma unroll
    for (int tm = 0; tm < 2; ++tm) {
        #pragma unroll
        for (int tn = 0; tn < 2; ++tn) {
            float s2[4];
            #pragma unroll
            for (int r = 0; r < 4; ++r) s2[r] = acc[tm][tn][r] * acc[tm][tn][r];
            #pragma unroll
            for (int m = 1; m <= 8; m <<= 1)
                #pragma unroll
                for (int r = 0; r < 4; ++r) s2[r] += __shfl_xor(s2[r], m);
            #pragma unroll
            for (int r = 0; r < 4; ++r) {
                size_t row = m0 + wm + tm * 16 + quad * 4 + r;
                float den = fmaxf(sqrtf(s2[r]), 1e-8f);
                float nvl = acc[tm][tn][r] / den;
                if (tn == 0) qa[row * RR + l16] = nvl * alf;
                else         kk[row * RR + l16] = nvl;
            }
        }
    }
}

// ---------------- phase A: per-chunk KV increments ----------------
__global__ __launch_bounds__(256) void incr_kernel(
    const bf16* __restrict__ hn, const float* __restrict__ kk,
    const float* __restrict__ pp, float* __restrict__ Inc) {
    __shared__ __attribute__((aligned(16))) float wjr[64][16];
    int t = threadIdx.x;
    int bc = blockIdx.x;
    int d0 = blockIdx.y * 256 + t;
    size_t row0 = (size_t)bc * 64;
    for (int idx = t; idx < 1024; idx += 256) {
        int j = idx >> 4, r = idx & 15;
        wjr[j][r] = kk[(row0 + j) * RR + r] * pp[PP_GP + r * 72 + (63 - j)];
    }
    __syncthreads();
    float acc[16] = {};
    for (int j = 0; j < 64; ++j) {
        float x = (float)hn[(row0 + j) * DD + d0];
        const float4* w4 = (const float4*)wjr[j];
        float4 w0 = w4[0], w1 = w4[1], w2 = w4[2], w3 = w4[3];
        acc[0]  += w0.x * x; acc[1]  += w0.y * x; acc[2]  += w0.z * x; acc[3]  += w0.w * x;
        acc[4]  += w1.x * x; acc[5]  += w1.y * x; acc[6]  += w1.z * x; acc[7]  += w1.w * x;
        acc[8]  += w2.x * x; acc[9]  += w2.y * x; acc[10] += w2.z * x; acc[11] += w2.w * x;
        acc[12] += w3.x * x; acc[13] += w3.y * x; acc[14] += w3.z * x; acc[15] += w3.w * x;
    }
    float* outp = Inc + (size_t)bc * 16 * 1024 + d0;
    #pragma unroll
    for (int r = 0; r < 16; ++r) outp[r * 1024] = acc[r];
}

// ---------------- phase B: sequential chunk-state scan ----------------
__global__ __launch_bounds__(256) void scan_kernel(
    const float* __restrict__ Inc, const float* __restrict__ pp,
    float* __restrict__ Sprev) {
    int gid = blockIdx.x * 256 + threadIdx.x;
    int b = gid >> 14, rd = gid & 16383;
    int r = rd >> 10;
    float gd = pp[PP_GP + r * 72 + 64];
    float s = 0.0f;
    for (int c = 0; c < 16; ++c) {
        size_t idx = ((size_t)(b * 16 + c) << 14) + rd;
        Sprev[idx] = s;
        s = s * gd + Inc[idx];
    }
}

// ---------------- phase C via MFMA: M(64x96) @ X(96x128) per block ----------
// K layout: [0..63] intra-chunk rows (attention + conv folded), [64..79] state
// rows (Sprev), [80..82] conv halo rows (prev chunk last 3), [83..95] zero pad.
#define XK 104   // padded K stride (bank-friendly, 16B-aligned rows)
__global__ __launch_bounds__(256, 2) void phasec_kernel(
    const bf16* __restrict__ hn, const float* __restrict__ qa, const float* __restrict__ kk,
    const float* __restrict__ Sprev, const float* __restrict__ pp,
    bf16* __restrict__ outpre) {
    __shared__ __attribute__((aligned(16))) bf16 Xt[128][XK];   // Xt[d][k]
    __shared__ __attribute__((aligned(16))) bf16 Mb[64][XK];
    __shared__ __attribute__((aligned(16))) float qa_s[64][16];
    __shared__ __attribute__((aligned(16))) float kk_s[64][16];
    __shared__ __attribute__((aligned(16))) float gpt[65][16];  // gpt[p][r]
    __shared__ float kks[4];
    int t = threadIdx.x;
    int bc = blockIdx.x;
    int c = bc & 15;
    int dt = blockIdx.y * 128;
    size_t row0 = (size_t)bc * 64;
    // ---- stage phase 1 ----
    for (int idx = t; idx < 1024; idx += 256) {
        int j = idx >> 4, r = idx & 15;
        qa_s[j][r] = qa[(row0 + j) * RR + r];
        kk_s[j][r] = kk[(row0 + j) * RR + r];
    }
    for (int idx = t; idx < 16 * 65; idx += 256) {
        int p = idx >> 4, r = idx & 15;
        gpt[p][r] = pp[PP_GP + r * 72 + p];
    }
    if (t < 4) kks[t] = pp[PP_KKER + t];
    // hn rows -> Xt[d][0..63]
    for (int idx = t; idx < 64 * 32; idx += 256) {
        int j = idx >> 5, ch = idx & 31;
        bf16x4 hv = *(const bf16x4*)(hn + (row0 + j) * DD + dt + ch * 4);
        #pragma unroll
        for (int e = 0; e < 4; ++e) Xt[ch * 4 + e][j] = hv[e];
    }
    // Sprev -> Xt[d][64..79]
    for (int idx = t; idx < 16 * 128; idx += 256) {
        int r = idx >> 7, dd = idx & 127;
        Xt[dd][64 + r] = (bf16)Sprev[((size_t)bc << 14) + r * 1024 + dt + dd];
    }
    // halo rows + zero pad -> Xt[d][80..95]
    for (int idx = t; idx < 128 * 16; idx += 256) {
        int dd = idx >> 4, p = idx & 15;
        bf16 val = (bf16)0.0f;
        if (p < 3 && c > 0) val = hn[(row0 - 3 + p) * DD + dt + dd];
        Xt[dd][80 + p] = val;
    }
    __syncthreads();
    // ---- build M (bf16) ----
    for (int idx = t; idx < 64 * 96; idx += 256) {
        int ii = idx / 96, jj = idx - ii * 96;
        float val = 0.0f;
        if (jj < 64) {
            if (jj <= ii) {
                const float4* qa4 = (const float4*)qa_s[ii];
                const float4* kk4 = (const float4*)kk_s[jj];
                const float4* gp4 = (const float4*)gpt[ii - jj];
                float s = 0.0f;
                #pragma unroll
                for (int x = 0; x < 4; ++x) {
                    float4 qv = qa4[x], kv = kk4[x], gv = gp4[x];
                    s += qv.x*kv.x*gv.x + qv.y*kv.y*gv.y + qv.z*kv.z*gv.z + qv.w*kv.w*gv.w;
                }
                val = s;
                if (ii - jj <= 3) val += kks[ii - jj];   // conv folded in
            }
        } else if (jj < 80) {
            int r = jj - 64;
            val = qa_s[ii][r] * gpt[ii + 1][r];
        } else if (jj < 83) {
            int p = jj - 80;                              // halo conv coeff
            if (ii <= p) val = kks[ii + 3 - p];
        }
        Mb[ii][jj] = (bf16)val;
    }
    __syncthreads();
    // ---- MFMA: wave w handles rows w*16.., all 8 col-tiles ----
    int lane = t & 63, w = t >> 6;
    int quad = lane >> 4, l16 = lane & 15;
    floatx4 acc[8] = {};
    #pragma unroll
    for (int ks = 0; ks < 3; ++ks) {
        bf16x8 af = *(const bf16x8*)(&Mb[w * 16 + l16][ks * 32 + quad * 8]);
        #pragma unroll
        for (int tn = 0; tn < 8; ++tn) {
            bf16x8 bfr = *(const bf16x8*)(&Xt[tn * 16 + l16][ks * 32 + quad * 8]);
            acc[tn] = __builtin_amdgcn_mfma_f32_16x16x32_bf16(af, bfr, acc[tn], 0, 0, 0);
        }
    }
    #pragma unroll
    for (int tn = 0; tn < 8; ++tn) {
        #pragma unroll
        for (int r = 0; r < 4; ++r) {
            size_t ii = w * 16 + quad * 4 + r;
            outpre[(row0 + ii) * DD + dt + tn * 16 + l16] = (bf16)acc[tn][r];
        }
    }
}

// ---------------- weight conversion ----------------
__global__ void cvt_bf16_kernel(const float* __restrict__ in, bf16* __restrict__ out, int n4) {
    int i = blockIdx.x * 256 + threadIdx.x;
    if (i < n4) {
        float4 v = ((const float4*)in)[i];
        bf16x4 o = { (bf16)v.x, (bf16)v.y, (bf16)v.z, (bf16)v.w };
        ((bf16x4*)out)[i] = o;
    }
}

__global__ __launch_bounds__(256) void trcvt_kernel(
    const float* __restrict__ in, bf16* __restrict__ out, int K, int N) {
    __shared__ float tl[32][33];
    int x0 = blockIdx.x * 32, y0 = blockIdx.y * 32;
    int tx = threadIdx.x & 31, ty = threadIdx.x >> 5;
    #pragma unroll
    for (int i = 0; i < 4; ++i)
        tl[ty + i * 8][tx] = in[(size_t)(y0 + ty + i * 8) * N + x0 + tx];
    __syncthreads();
    #pragma unroll
    for (int i = 0; i < 4; ++i)
        out[(size_t)(x0 + ty + i * 8) * K + y0 + tx] = (bf16)tl[tx][ty + i * 8];
}

// ---------------- MFMA GEMM, templated BK, XOR-swizzled LDS, XCD cohorts ----
template <int EPI, int BK>
__global__ __launch_bounds__(256, 2) void gemm_bt_kernel(
    const bf16* __restrict__ A, const bf16* __restrict__ Bt,
    const float* __restrict__ bias, const float* __restrict__ resid,
    float* __restrict__ outf, bf16* __restrict__ outb, int K, int N) {
    constexpr int CH = BK / 8;              // 16B chunks per row
    constexpr int PT = 128 * CH / 256;      // staging slots per thread per matrix
    __shared__ __attribute__((aligned(16))) bf16 As[128 * BK];
    __shared__ __attribute__((aligned(16))) bf16 Bs[128 * BK];
    int tid = threadIdx.x, lane = tid & 63, wid = tid >> 6;
    int quad = lane >> 4, l16 = lane & 15;
    int lb = blockIdx.y * gridDim.x + blockIdx.x;
    int xcd = lb & 7, q = lb >> 3;
    int m0 = (xcd * 8 + (q & 7)) * 128;
    int n0 = (q >> 3) * 128;
    int wm = (wid >> 1) * 64, wn = (wid & 1) * 64;
    const bf16* Ap[PT]; const bf16* Bp[PT]; int lo[PT];
    #pragma unroll
    for (int j = 0; j < PT; ++j) {
        int s = j * 256 + tid;
        int row = s / CH, cc = s % CH;
        int gc = cc ^ (row & (CH - 1));
        Ap[j] = A  + (size_t)(m0 + row) * K + gc * 8;
        Bp[j] = Bt + (size_t)(n0 + row) * K + gc * 8;
        lo[j] = s * 8;
    }
    floatx4 acc[4][4] = {};
    for (int kt = 0; kt < K; kt += BK) {
        #pragma unroll
        for (int j = 0; j < PT; ++j) {
            g2l16(Ap[j] + kt, As + lo[j]);
            g2l16(Bp[j] + kt, Bs + lo[j]);
        }
        __syncthreads();
        #pragma unroll
        for (int ks = 0; ks < BK / 32; ++ks) {
            bf16x8 af[4], bfr[4];
            #pragma unroll
            for (int tm = 0; tm < 4; ++tm) {
                int row = wm + tm * 16 + l16;
                int cc = (ks * 4 + quad) ^ (row & (CH - 1));
                af[tm] = *(const bf16x8*)(As + row * BK + cc * 8);
            }
            #pragma unroll
            for (int tn = 0; tn < 4; ++tn) {
                int row = wn + tn * 16 + l16;
                int cc = (ks * 4 + quad) ^ (row & (CH - 1));
                bfr[tn] = *(const bf16x8*)(Bs + row * BK + cc * 8);
            }
            #pragma unroll
            for (int tm = 0; tm < 4; ++tm)
                #pragma unroll
                for (int tn = 0; tn < 4; ++tn)
                    acc[tm][tn] = __builtin_amdgcn_mfma_f32_16x16x32_bf16(
                        af[tm], bfr[tn], acc[tm][tn], 0, 0, 0);
        }
        __syncthreads();
    }
    #pragma unroll
    for (int tn = 0; tn < 4; ++tn) {
        int gn = n0 + wn + tn * 16 + l16;
        float bs = bias[gn];
        #pragma unroll
        for (int tm = 0; tm < 4; ++tm) {
            #pragma unroll
            for (int r = 0; r < 4; ++r) {
                size_t gm = (size_t)m0 + wm + tm * 16 + quad * 4 + r;
                float v = acc[tm][tn][r] + bs;
                if (EPI == 1) {
                    outb[gm * N + gn] = (bf16)gelu_f(v);
                } else {
                    v += resid[gm * N + gn];
                    outf[gm * N + gn] = v;
                }
            }
        }
    }
}

// ---------------- launch ----------------
extern "C" void kernel_launch(void* const* d_in, const int* in_sizes, int n_in,
                              void* d_out, int out_size, void* d_ws, size_t ws_size,
                              hipStream_t stream) {
    const float* h           = (const float*)d_in[0];
    const float* u           = (const float*)d_in[1];
    const float* v           = (const float*)d_in[2];
    const float* decay_logit = (const float*)d_in[3];
    const float* alpha_logit = (const float*)d_in[4];
    const float* gate_logit  = (const float*)d_in[5];
    const float* kbase       = (const float*)d_in[6];
    const float* proj_w      = (const float*)d_in[7];
    const float* proj_b      = (const float*)d_in[8];
    const float* norm1_w     = (const float*)d_in[9];
    const float* norm2_w     = (const float*)d_in[10];
    const float* mlp_w1      = (const float*)d_in[11];
    const float* mlp_b1      = (const float*)d_in[12];
    const float* mlp_w2      = (const float*)d_in[13];
    const float* mlp_b2      = (const float*)d_in[14];
    float* out = (float*)d_out;

    char* wsb = (char*)d_ws;
    size_t off = 0;
    auto alloc = [&](size_t bytes) -> void* {
        void* p = wsb + off;
        off += (bytes + 255) & ~(size_t)255;
        return p;
    };
    float* pp     = (float*)alloc(PP_FLOATS * 4);
    bf16*  Ut     = (bf16*) alloc((size_t)32 * 1024 * 2);
    bf16*  hn     = (bf16*) alloc((size_t)8192 * 1024 * 2);
    float* qa     = (float*)alloc((size_t)8192 * 16 * 4);
    float* kk     = (float*)alloc((size_t)8192 * 16 * 4);
    float* Inc    = (float*)alloc((size_t)128 * 16 * 1024 * 4);
    float* Sprev  = (float*)alloc((size_t)128 * 16 * 1024 * 4);
    bf16*  outpre = (bf16*) alloc((size_t)8192 * 1024 * 2);
    float* h2     = (float*)alloc((size_t)8192 * 1024 * 4);
    bf16*  hidden = (bf16*) alloc((size_t)8192 * 4096 * 2);
    bf16*  Wp     = (bf16*) alloc((size_t)1024 * 1024 * 2);
    bf16*  W1t    = (bf16*) alloc((size_t)4096 * 1024 * 2);
    bf16*  W2t    = (bf16*) alloc((size_t)1024 * 4096 * 2);
    bf16*  hn2 = hn;   // hn dead after phasec

    params_kernel<<<1, 64, 0, stream>>>(decay_logit, alpha_logit, gate_logit, kbase, pp);
    uvt_kernel<<<32, 256, 0, stream>>>(u, v, Ut);
    cvt_bf16_kernel<<<1024, 256, 0, stream>>>(proj_w, Wp, 1024 * 1024 / 4);
    trcvt_kernel<<<dim3(4096 / 32, 1024 / 32), 256, 0, stream>>>(mlp_w1, W1t, 1024, 4096);
    trcvt_kernel<<<dim3(1024 / 32, 4096 / 32), 256, 0, stream>>>(mlp_w2, W2t, 4096, 1024);
    rmsrow_kernel<<<8192, 256, 0, stream>>>(h, norm1_w, hn);
    qk_kernel<<<64, 256, 0, stream>>>(hn, Ut, pp, qa, kk);
    incr_kernel<<<dim3(128, 4), 256, 0, stream>>>(hn, kk, pp, Inc);
    scan_kernel<<<512, 256, 0, stream>>>(Inc, pp, Sprev);
    phasec_kernel<<<dim3(128, 8), 256, 0, stream>>>(hn, qa, kk, Sprev, pp, outpre);
    gemm_bt_kernel<0, 128><<<dim3(8, 64), 256, 0, stream>>>(outpre, Wp, proj_b, h, h2, nullptr, 1024, 1024);
    rmsrow_kernel<<<8192, 256, 0, stream>>>(h2, norm2_w, hn2);
    gemm_bt_kernel<1, 64><<<dim3(32, 64), 256, 0, stream>>>(hn2, W1t, mlp_b1, nullptr, nullptr, hidden, 1024, 4096);
    gemm_bt_kernel<2, 128><<<dim3(8, 64), 256, 0, stream>>>(hidden, W2t, mlp_b2, h2, out, nullptr, 4096, 1024);
}

// Round 4
// 374.799 us; speedup vs baseline: 1.2830x; 1.0515x over previous
//
#include <hip/hip_runtime.h>
#include <hip/hip_bf16.h>
#include <cstdint>
#include <cstddef>

// ---------------- types ----------------
typedef __bf16 bf16;
typedef __bf16 bf16x2 __attribute__((ext_vector_type(2)));
typedef __bf16 bf16x4 __attribute__((ext_vector_type(4)));
typedef __bf16 bf16x8 __attribute__((ext_vector_type(8)));
typedef float  floatx4 __attribute__((ext_vector_type(4)));

// problem constants
#define BB 8
#define SS 1024
#define DD 1024
#define RR 16
#define CHK 64
#define NCH 16

// params buffer layout (floats)
#define PP_ALPHA 0
#define PP_GAMMA 16
#define PP_GP    32           // 16*72: gamma^0..gamma^71 per r
#define PP_KKER  (32 + 16*72)
#define PP_FLOATS 2048

__device__ __forceinline__ float sigmoidf_(float x) { return 1.0f / (1.0f + __expf(-x)); }

__device__ __forceinline__ float gelu_f(float x) {
    float u = 0.7978845608028654f * (x + 0.044715f * x * x * x);
    float t = 1.0f - 2.0f / (__expf(2.0f * u) + 1.0f);
    return 0.5f * x * (1.0f + t);
}

__device__ __forceinline__ void g2l16(const bf16* g, bf16* l) {
    __builtin_amdgcn_global_load_lds(
        (const __attribute__((address_space(1))) void*)g,
        (__attribute__((address_space(3))) void*)l, 16, 0, 0);
}

// ---------------- fused prologue: params + uvt + cvt(Wp) + trcvt(W1,W2) -----
// block ranges: [0] params | [1,33) uvt | [33,1057) cvt Wp
//               [1057,2081) trcvt W1 (K=1024,N=4096) | [2081,3105) trcvt W2
__global__ __launch_bounds__(256) void prep_kernel(
    const float* __restrict__ decay_logit, const float* __restrict__ alpha_logit,
    const float* __restrict__ gate_logit,  const float* __restrict__ kbase,
    const float* __restrict__ u, const float* __restrict__ v,
    const float* __restrict__ proj_w, const float* __restrict__ mlp_w1,
    const float* __restrict__ mlp_w2,
    float* __restrict__ pp, bf16* __restrict__ Ut, bf16* __restrict__ Wp,
    bf16* __restrict__ W1t, bf16* __restrict__ W2t) {
    __shared__ float tl[64][69];
    int t = threadIdx.x;
    int bid = blockIdx.x;
    if (bid == 0) {
        if (t < 16) {
            pp[PP_ALPHA + t] = sigmoidf_(alpha_logit[t]);
            float g = sigmoidf_(decay_logit[t]);
            g = fminf(fmaxf(g, 0.15f), 1.0f);
            pp[PP_GAMMA + t] = g;
            float acc = 1.0f;
            for (int p = 0; p < 72; ++p) { pp[PP_GP + t * 72 + p] = acc; acc *= g; }
        }
        if (t >= 16 && t < 20) {
            float gate = sigmoidf_(gate_logit[0]);
            pp[PP_KKER + (t - 16)] = gate * kbase[t - 16];
        }
        return;
    }
    if (bid < 33) {
        int c = bid - 1;
        const float* src = (c < 16) ? u : v;
        int cc = c & 15;
        for (int d = t; d < 1024; d += 256)
            Ut[c * 1024 + d] = (bf16)src[d * 16 + cc];
        return;
    }
    if (bid < 1057) {
        int i = (bid - 33) * 256 + t;
        float4 w = ((const float4*)proj_w)[i];
        bf16x4 o = { (bf16)w.x, (bf16)w.y, (bf16)w.z, (bf16)w.w };
        ((bf16x4*)Wp)[i] = o;
        return;
    }
    // 64x64 transpose-convert tiles
    const float* in; bf16* outp; int K, N, tb;
    if (bid < 2081) { in = mlp_w1; outp = W1t; K = 1024; N = 4096; tb = bid - 1057; }
    else            { in = mlp_w2; outp = W2t; K = 4096; N = 1024; tb = bid - 2081; }
    int nx = N >> 6;
    int x0 = (tb % nx) * 64, y0 = (tb / nx) * 64;
    int tx = t & 15, ty = t >> 4;
    #pragma unroll
    for (int i = 0; i < 4; ++i) {
        float4 w = *(const float4*)(in + (size_t)(y0 + ty + i * 16) * N + x0 + tx * 4);
        tl[ty + i * 16][tx * 4 + 0] = w.x; tl[ty + i * 16][tx * 4 + 1] = w.y;
        tl[ty + i * 16][tx * 4 + 2] = w.z; tl[ty + i * 16][tx * 4 + 3] = w.w;
    }
    __syncthreads();
    #pragma unroll
    for (int i = 0; i < 4; ++i) {
        int nl = ty + i * 16;
        bf16x4 o = { (bf16)tl[tx * 4 + 0][nl], (bf16)tl[tx * 4 + 1][nl],
                     (bf16)tl[tx * 4 + 2][nl], (bf16)tl[tx * 4 + 3][nl] };
        *(bf16x4*)(outp + (size_t)(x0 + nl) * K + y0 + tx * 4) = o;
    }
}

// ---------------- generic rmsnorm row kernel (fp32 in, bf16 out) ------------
__global__ __launch_bounds__(256) void rmsrow_kernel(
    const float* __restrict__ x, const float* __restrict__ nw, bf16* __restrict__ y) {
    __shared__ float red[4];
    int t = threadIdx.x;
    size_t row = blockIdx.x;
    float4 hv = ((const float4*)(x + row * DD))[t];
    float ss = hv.x*hv.x + hv.y*hv.y + hv.z*hv.z + hv.w*hv.w;
    for (int m = 32; m; m >>= 1) ss += __shfl_xor(ss, m);
    if ((t & 63) == 0) red[t >> 6] = ss;
    __syncthreads();
    float tot = red[0] + red[1] + red[2] + red[3];
    float rinv = rsqrtf(tot * (1.0f / 1024.0f) + 1e-6f);
    float4 wv = ((const float4*)nw)[t];
    bf16x4 o = { (bf16)(hv.x * rinv * wv.x), (bf16)(hv.y * rinv * wv.y),
                 (bf16)(hv.z * rinv * wv.z), (bf16)(hv.w * rinv * wv.w) };
    ((bf16x4*)(y + row * DD))[t] = o;
}

// ---------------- qk projection + l2norm via MFMA, 32-row tiles -------------
__global__ __launch_bounds__(256) void qk_kernel(
    const bf16* __restrict__ hn, const bf16* __restrict__ Ut,
    const float* __restrict__ pp, float* __restrict__ qa, float* __restrict__ kk) {
    __shared__ __attribute__((aligned(16))) bf16 As[32 * 64];
    __shared__ __attribute__((aligned(16))) bf16 Bs[32 * 64];
    int tid = threadIdx.x, lane = tid & 63, wid = tid >> 6;
    int quad = lane >> 4, l16 = lane & 15;
    int m0 = blockIdx.x * 32;
    int mt = wid >> 1, nt = wid & 1;
    int s_row = tid >> 3, s_cc = tid & 7;
    int s_gc = s_cc ^ (s_row & 7);
    const bf16* Ap = hn + (size_t)(m0 + s_row) * DD + s_gc * 8;
    const bf16* Bp = Ut + (size_t)s_row * DD + s_gc * 8;
    int slo = tid * 8;
    floatx4 acc = {};
    for (int kt = 0; kt < 1024; kt += 64) {
        g2l16(Ap + kt, As + slo);
        g2l16(Bp + kt, Bs + slo);
        __syncthreads();
        #pragma unroll
        for (int ks = 0; ks < 2; ++ks) {
            int arow = mt * 16 + l16;
            int acc_ = (ks * 4 + quad) ^ (arow & 7);
            bf16x8 af = *(const bf16x8*)(As + arow * 64 + acc_ * 8);
            int brow = nt * 16 + l16;
            int bcc = (ks * 4 + quad) ^ (brow & 7);
            bf16x8 bfr = *(const bf16x8*)(Bs + brow * 64 + bcc * 8);
            acc = __builtin_amdgcn_mfma_f32_16x16x32_bf16(af, bfr, acc, 0, 0, 0);
        }
        __syncthreads();
    }
    float alf = pp[PP_ALPHA + l16];
    float s2[4];
    #pragma unroll
    for (int r = 0; r < 4; ++r) s2[r] = acc[r] * acc[r];
    #pragma unroll
    for (int m = 1; m <= 8; m <<= 1)
        #pragma unroll
        for (int r = 0; r < 4; ++r) s2[r] += __shfl_xor(s2[r], m);
    #pragma unroll
    for (int r = 0; r < 4; ++r) {
        size_t row = m0 + mt * 16 + quad * 4 + r;
        float den = fmaxf(sqrtf(s2[r]), 1e-8f);
        float nvl = acc[r] / den;
        if (nt == 0) qa[row * RR + l16] = nvl * alf;
        else         kk[row * RR + l16] = nvl;
    }
}

// ---------------- phase A: per-chunk KV increments ----------------
__global__ __launch_bounds__(256) void incr_kernel(
    const bf16* __restrict__ hn, const float* __restrict__ kk,
    const float* __restrict__ pp, float* __restrict__ Inc) {
    __shared__ __attribute__((aligned(16))) float wjr[64][16];
    int t = threadIdx.x;
    int bc = blockIdx.x;
    int d0 = blockIdx.y * 512 + t * 2;
    size_t row0 = (size_t)bc * 64;
    for (int idx = t; idx < 1024; idx += 256) {
        int j = idx >> 4, r = idx & 15;
        wjr[j][r] = kk[(row0 + j) * RR + r] * pp[PP_GP + r * 72 + (63 - j)];
    }
    __syncthreads();
    float acc0[16] = {}, acc1[16] = {};
    for (int j = 0; j < 64; ++j) {
        bf16x2 hv = *(const bf16x2*)(hn + (row0 + j) * DD + d0);
        float x0 = (float)hv[0], x1 = (float)hv[1];
        const float4* w4 = (const float4*)wjr[j];
        #pragma unroll
        for (int g = 0; g < 4; ++g) {
            float4 w = w4[g];
            acc0[g*4+0] += w.x * x0; acc0[g*4+1] += w.y * x0;
            acc0[g*4+2] += w.z * x0; acc0[g*4+3] += w.w * x0;
            acc1[g*4+0] += w.x * x1; acc1[g*4+1] += w.y * x1;
            acc1[g*4+2] += w.z * x1; acc1[g*4+3] += w.w * x1;
        }
    }
    float* outp = Inc + (size_t)bc * 16 * 1024 + d0;
    #pragma unroll
    for (int r = 0; r < 16; ++r) {
        float2 o = { acc0[r], acc1[r] };
        *(float2*)&outp[r * 1024] = o;
    }
}

// ---------------- phase B: sequential chunk-state scan ----------------
__global__ __launch_bounds__(256) void scan_kernel(
    const float* __restrict__ Inc, const float* __restrict__ pp,
    float* __restrict__ Sprev) {
    int gid = blockIdx.x * 256 + threadIdx.x;
    int b = gid >> 14, rd = gid & 16383;
    int r = rd >> 10;
    float gd = pp[PP_GP + r * 72 + 64];
    float s = 0.0f;
    for (int c = 0; c < 16; ++c) {
        size_t idx = ((size_t)(b * 16 + c) << 14) + rd;
        Sprev[idx] = s;
        s = s * gd + Inc[idx];
    }
}

// ---------------- phase C via MFMA: M(64x96) @ X(96x1024-slice) -------------
// K layout: [0..63] intra rows (attn + conv folded), [64..79] state rows,
// [80..82] conv halo rows, [83..95] zero. M built once, used for 2 d-tiles.
#define XK 104
__global__ __launch_bounds__(256, 2) void phasec_kernel(
    const bf16* __restrict__ hn, const float* __restrict__ qa, const float* __restrict__ kk,
    const float* __restrict__ Sprev, const float* __restrict__ pp,
    bf16* __restrict__ outpre) {
    __shared__ __attribute__((aligned(16))) bf16 Xt[128][XK];
    __shared__ __attribute__((aligned(16))) bf16 Mb[64][XK];
    __shared__ __attribute__((aligned(16))) float qa_s[64][16];
    __shared__ __attribute__((aligned(16))) float kk_s[64][16];
    __shared__ __attribute__((aligned(16))) float gpt[65][16];
    __shared__ float kks[4];
    int t = threadIdx.x;
    int bc = blockIdx.x;
    int c = bc & 15;
    size_t row0 = (size_t)bc * 64;
    for (int idx = t; idx < 1024; idx += 256) {
        int j = idx >> 4, r = idx & 15;
        qa_s[j][r] = qa[(row0 + j) * RR + r];
        kk_s[j][r] = kk[(row0 + j) * RR + r];
    }
    for (int idx = t; idx < 16 * 65; idx += 256) {
        int p = idx >> 4, r = idx & 15;
        gpt[p][r] = pp[PP_GP + r * 72 + p];
    }
    if (t < 4) kks[t] = pp[PP_KKER + t];
    __syncthreads();
    for (int idx = t; idx < 64 * 96; idx += 256) {
        int ii = idx / 96, jj = idx - ii * 96;
        float val = 0.0f;
        if (jj < 64) {
            if (jj <= ii) {
                const float4* qa4 = (const float4*)qa_s[ii];
                const float4* kk4 = (const float4*)kk_s[jj];
                const float4* gp4 = (const float4*)gpt[ii - jj];
                float s = 0.0f;
                #pragma unroll
                for (int x = 0; x < 4; ++x) {
                    float4 qv = qa4[x], kv = kk4[x], gv = gp4[x];
                    s += qv.x*kv.x*gv.x + qv.y*kv.y*gv.y + qv.z*kv.z*gv.z + qv.w*kv.w*gv.w;
                }
                val = s;
                if (ii - jj <= 3) val += kks[ii - jj];
            }
        } else if (jj < 80) {
            int r = jj - 64;
            val = qa_s[ii][r] * gpt[ii + 1][r];
        } else if (jj < 83) {
            int p = jj - 80;
            if (ii <= p) val = kks[ii + 3 - p];
        }
        Mb[ii][jj] = (bf16)val;
    }
    int lane = t & 63, w = t >> 6, quad = lane >> 4, l16 = lane & 15;
    for (int it = 0; it < 2; ++it) {
        int dt = blockIdx.y * 256 + it * 128;
        __syncthreads();
        // hn -> Xt transpose (per-lane rotated writes: 16-way -> 8-way conflicts)
        for (int idx = t; idx < 64 * 32; idx += 256) {
            int j = idx >> 5, ch = idx & 31;
            bf16x4 hv = *(const bf16x4*)(hn + (row0 + j) * DD + dt + ch * 4);
            #pragma unroll
            for (int ee = 0; ee < 4; ++ee) {
                int e = (ee + t) & 3;
                Xt[ch * 4 + e][j] = hv[e];
            }
        }
        for (int idx = t; idx < 16 * 128; idx += 256) {
            int r = idx >> 7, dd = idx & 127;
            Xt[dd][64 + r] = (bf16)Sprev[((size_t)bc << 14) + r * 1024 + dt + dd];
        }
        for (int idx = t; idx < 128 * 16; idx += 256) {
            int dd = idx >> 4, p = idx & 15;
            bf16 val = (bf16)0.0f;
            if (p < 3 && c > 0) val = hn[(row0 - 3 + p) * DD + dt + dd];
            Xt[dd][80 + p] = val;
        }
        __syncthreads();
        floatx4 acc[8] = {};
        #pragma unroll
        for (int ks = 0; ks < 3; ++ks) {
            bf16x8 af = *(const bf16x8*)(&Mb[w * 16 + l16][ks * 32 + quad * 8]);
            #pragma unroll
            for (int tn = 0; tn < 8; ++tn) {
                bf16x8 bfr = *(const bf16x8*)(&Xt[tn * 16 + l16][ks * 32 + quad * 8]);
                acc[tn] = __builtin_amdgcn_mfma_f32_16x16x32_bf16(af, bfr, acc[tn], 0, 0, 0);
            }
        }
        #pragma unroll
        for (int tn = 0; tn < 8; ++tn) {
            #pragma unroll
            for (int r = 0; r < 4; ++r) {
                size_t ii = w * 16 + quad * 4 + r;
                outpre[(row0 + ii) * DD + dt + tn * 16 + l16] = (bf16)acc[tn][r];
            }
        }
    }
}

// ---------------- MFMA GEMM, templated BK, XOR-swizzled LDS, XCD cohorts ----
template <int EPI, int BK>
__global__ __launch_bounds__(256, 2) void gemm_bt_kernel(
    const bf16* __restrict__ A, const bf16* __restrict__ Bt,
    const float* __restrict__ bias, const float* __restrict__ resid,
    float* __restrict__ outf, bf16* __restrict__ outb, int K, int N) {
    constexpr int CH = BK / 8;
    constexpr int PT = 128 * CH / 256;
    __shared__ __attribute__((aligned(16))) bf16 As[128 * BK];
    __shared__ __attribute__((aligned(16))) bf16 Bs[128 * BK];
    int tid = threadIdx.x, lane = tid & 63, wid = tid >> 6;
    int quad = lane >> 4, l16 = lane & 15;
    int lb = blockIdx.y * gridDim.x + blockIdx.x;
    int xcd = lb & 7, q = lb >> 3;
    int m0 = (xcd * 8 + (q & 7)) * 128;
    int n0 = (q >> 3) * 128;
    int wm = (wid >> 1) * 64, wn = (wid & 1) * 64;
    const bf16* Ap[PT]; const bf16* Bp[PT]; int lo[PT];
    #pragma unroll
    for (int j = 0; j < PT; ++j) {
        int s = j * 256 + tid;
        int row = s / CH, cc = s % CH;
        int gc = cc ^ (row & (CH - 1));
        Ap[j] = A  + (size_t)(m0 + row) * K + gc * 8;
        Bp[j] = Bt + (size_t)(n0 + row) * K + gc * 8;
        lo[j] = s * 8;
    }
    floatx4 acc[4][4] = {};
    for (int kt = 0; kt < K; kt += BK) {
        #pragma unroll
        for (int j = 0; j < PT; ++j) {
            g2l16(Ap[j] + kt, As + lo[j]);
            g2l16(Bp[j] + kt, Bs + lo[j]);
        }
        __syncthreads();
        #pragma unroll
        for (int ks = 0; ks < BK / 32; ++ks) {
            bf16x8 af[4], bfr[4];
            #pragma unroll
            for (int tm = 0; tm < 4; ++tm) {
                int row = wm + tm * 16 + l16;
                int cc = (ks * 4 + quad) ^ (row & (CH - 1));
                af[tm] = *(const bf16x8*)(As + row * BK + cc * 8);
            }
            #pragma unroll
            for (int tn = 0; tn < 4; ++tn) {
                int row = wn + tn * 16 + l16;
                int cc = (ks * 4 + quad) ^ (row & (CH - 1));
                bfr[tn] = *(const bf16x8*)(Bs + row * BK + cc * 8);
            }
            #pragma unroll
            for (int tm = 0; tm < 4; ++tm)
                #pragma unroll
                for (int tn = 0; tn < 4; ++tn)
                    acc[tm][tn] = __builtin_amdgcn_mfma_f32_16x16x32_bf16(
                        af[tm], bfr[tn], acc[tm][tn], 0, 0, 0);
        }
        __syncthreads();
    }
    #pragma unroll
    for (int tn = 0; tn < 4; ++tn) {
        int gn = n0 + wn + tn * 16 + l16;
        float bs = bias[gn];
        #pragma unroll
        for (int tm = 0; tm < 4; ++tm) {
            #pragma unroll
            for (int r = 0; r < 4; ++r) {
                size_t gm = (size_t)m0 + wm + tm * 16 + quad * 4 + r;
                float v = acc[tm][tn][r] + bs;
                if (EPI == 1) {
                    outb[gm * N + gn] = (bf16)gelu_f(v);
                } else {
                    v += resid[gm * N + gn];
                    outf[gm * N + gn] = v;
                }
            }
        }
    }
}

// ---------------- launch ----------------
extern "C" void kernel_launch(void* const* d_in, const int* in_sizes, int n_in,
                              void* d_out, int out_size, void* d_ws, size_t ws_size,
                              hipStream_t stream) {
    const float* h           = (const float*)d_in[0];
    const float* u           = (const float*)d_in[1];
    const float* v           = (const float*)d_in[2];
    const float* decay_logit = (const float*)d_in[3];
    const float* alpha_logit = (const float*)d_in[4];
    const float* gate_logit  = (const float*)d_in[5];
    const float* kbase       = (const float*)d_in[6];
    const float* proj_w      = (const float*)d_in[7];
    const float* proj_b      = (const float*)d_in[8];
    const float* norm1_w     = (const float*)d_in[9];
    const float* norm2_w     = (const float*)d_in[10];
    const float* mlp_w1      = (const float*)d_in[11];
    const float* mlp_b1      = (const float*)d_in[12];
    const float* mlp_w2      = (const float*)d_in[13];
    const float* mlp_b2      = (const float*)d_in[14];
    float* out = (float*)d_out;

    char* wsb = (char*)d_ws;
    size_t off = 0;
    auto alloc = [&](size_t bytes) -> void* {
        void* p = wsb + off;
        off += (bytes + 255) & ~(size_t)255;
        return p;
    };
    float* pp     = (float*)alloc(PP_FLOATS * 4);
    bf16*  Ut     = (bf16*) alloc((size_t)32 * 1024 * 2);
    bf16*  hn     = (bf16*) alloc((size_t)8192 * 1024 * 2);
    float* qa     = (float*)alloc((size_t)8192 * 16 * 4);
    float* kk     = (float*)alloc((size_t)8192 * 16 * 4);
    float* Inc    = (float*)alloc((size_t)128 * 16 * 1024 * 4);
    float* Sprev  = (float*)alloc((size_t)128 * 16 * 1024 * 4);
    bf16*  outpre = (bf16*) alloc((size_t)8192 * 1024 * 2);
    float* h2     = (float*)alloc((size_t)8192 * 1024 * 4);
    bf16*  hidden = (bf16*) alloc((size_t)8192 * 4096 * 2);
    bf16*  Wp     = (bf16*) alloc((size_t)1024 * 1024 * 2);
    bf16*  W1t    = (bf16*) alloc((size_t)4096 * 1024 * 2);
    bf16*  W2t    = (bf16*) alloc((size_t)1024 * 4096 * 2);
    bf16*  hn2 = hn;   // hn dead after phasec

    prep_kernel<<<3105, 256, 0, stream>>>(decay_logit, alpha_logit, gate_logit, kbase,
                                          u, v, proj_w, mlp_w1, mlp_w2,
                                          pp, Ut, Wp, W1t, W2t);
    rmsrow_kernel<<<8192, 256, 0, stream>>>(h, norm1_w, hn);
    qk_kernel<<<256, 256, 0, stream>>>(hn, Ut, pp, qa, kk);
    incr_kernel<<<dim3(128, 2), 256, 0, stream>>>(hn, kk, pp, Inc);
    scan_kernel<<<512, 256, 0, stream>>>(Inc, pp, Sprev);
    phasec_kernel<<<dim3(128, 4), 256, 0, stream>>>(hn, qa, kk, Sprev, pp, outpre);
    gemm_bt_kernel<0, 128><<<dim3(8, 64), 256, 0, stream>>>(outpre, Wp, proj_b, h, h2, nullptr, 1024, 1024);
    rmsrow_kernel<<<8192, 256, 0, stream>>>(h2, norm2_w, hn2);
    gemm_bt_kernel<1, 64><<<dim3(32, 64), 256, 0, stream>>>(hn2, W1t, mlp_b1, nullptr, nullptr, hidden, 1024, 4096);
    gemm_bt_kernel<2, 128><<<dim3(8, 64), 256, 0, stream>>>(hidden, W2t, mlp_b2, h2, out, nullptr, 4096, 1024);
}